// Round 9
// baseline (51.193 us; speedup 1.0000x reference)
//
#include <hip/hip_runtime.h>
#include <math.h>

#define NPTS 8192
#define LOSCALE 2048.0f
#define INVLO   (1.0f / 2048.0f)

typedef _Float16 half8  __attribute__((ext_vector_type(8)));
typedef float    f32x16 __attribute__((ext_vector_type(16)));

__device__ __forceinline__ float min3a(float m, float a, float b) {
    float r;
    asm("v_min3_f32 %0, %1, %2, %3" : "=v"(r) : "v"(m), "v"(a), "v"(b));
    return r;
}

// ---------------------------------------------------------------------------
// dist(q,p) = qn + pn - 2 q.p via TWO 32x32x16_f16 MFMAs (hi + scaled-lo),
// permutation-proof: qn,pn ride k-channels (no external row/col indexing);
// per-query threshold+SUM is invariant to any bijective row/col mapping;
// identical A/B k-forms cancel any k-permutation (R7 evidence: 32x32 forms
// match). Lo terms pre-scaled by 2048 so they are normal f16 (kills the
// denormal-flush error that sank R7):  dist = D_hi + D_lo * (1/2048).
//   hi: A{ahx,ahy,ahz,qnh,one,0,0,0} . B{phx,phy,phz,one,pnh,0,0,0}
//   lo: A{alx,aly,alz,ahx,ahy,ahz,qnl,one} . B{phx,phy,phz,plx,ply,plz,one,pnl}
// (a=-2q; *h=f16(v); *l=f16((v-vh)*2048); dropped al.pl/2048^2 ~ 1e-9.)
// Only lane-half h==0 carries data; h==1 fragments are zero.
// C/D layout (m74/m101 verified, dtype-independent): col=lane&31,
// row=(reg&3)+8*(reg>>2)+4*(lane>>5).
// ---------------------------------------------------------------------------

// Prep: B-fragments (hi,lo) for all 8 (set,batch) combos -> ws (2 MiB).
// One thread per (combo, tile, col): 8*256*32 = 65536 threads.
__global__ __launch_bounds__(256) void prep_bfrag(
    const float* __restrict__ xyz1,
    const float* __restrict__ xyz2,
    half8* __restrict__ bfrag)
{
    const int gid  = blockIdx.x * 256 + threadIdx.x;
    const int col  = gid & 31;
    const int tile = (gid >> 5) & 255;
    const int c    = gid >> 13;            // set*4 + b
    const int s    = c >> 2, bb = c & 3;
    const float* src = (s == 0 ? xyz1 : xyz2)
                     + ((size_t)bb * NPTS + tile * 32 + col) * 3;
    const float px = src[0], py = src[1], pz = src[2];
    const _Float16 phx = (_Float16)px, phy = (_Float16)py, phz = (_Float16)pz;
    const _Float16 plx = (_Float16)((px - (float)phx) * LOSCALE);
    const _Float16 ply = (_Float16)((py - (float)phy) * LOSCALE);
    const _Float16 plz = (_Float16)((pz - (float)phz) * LOSCALE);
    const float pn = px * px + py * py + pz * pz;
    const _Float16 pnh = (_Float16)pn;
    const _Float16 pnl = (_Float16)((pn - (float)pnh) * LOSCALE);
    const _Float16 one = (_Float16)1.0f, z = (_Float16)0.0f;
    half8 hi = (half8){phx, phy, phz, one, pnh, z, z, z};
    half8 lo = (half8){phx, phy, phz, plx, ply, plz, one, pnl};
    half8* dst = bfrag + ((size_t)(c * 256 + tile) * 2) * 32 + col;
    dst[0]  = hi;
    dst[32] = lo;
}

// Main: 256 blocks = (dir, b, qchunk of 256 queries). 8 waves: wave w
// handles query tiles (w>>2)*4..+3 (A hi/lo in regs) x point quarter (w&3)
// = 64 point tiles streamed in pairs from ws (L2-hot, prefetched).
// Per pair per q-tile: 4 mfma + 32 fma + 16 v_min3.
__global__ __launch_bounds__(512, 2) void chamfer_mfma(
    const float* __restrict__ xyz1,
    const float* __restrict__ xyz2,
    const half8* __restrict__ bfrag,
    const float* __restrict__ thp,
    double* __restrict__ partial)
{
    __shared__ float  red[8][4][32];
    __shared__ double wsum[8];

    const int bid    = blockIdx.x;
    const int qchunk = bid & 31;
    const int combo  = bid >> 5;            // dir*4 + b
    const int b      = combo & 3;
    const int dir    = combo >> 2;
    const float* Q   = (dir == 0 ? xyz1 : xyz2) + (size_t)b * NPTS * 3;
    const int   cref = (dir == 0 ? 4 : 0) + b;   // fragments of opposite set

    const int lane = threadIdx.x & 63;
    const int w    = threadIdx.x >> 6;
    const int h    = lane >> 5;
    const int col  = lane & 31;
    const int qg   = w >> 2;                // 0..1: query-tile group
    const int pq   = w & 3;                 // 0..3: point quarter

    const _Float16 one = (_Float16)1.0f, z16 = (_Float16)0.0f;
    const half8 zfrag = (half8){z16, z16, z16, z16, z16, z16, z16, z16};

    half8 Ah[4], Al[4];
    f32x16 m[4];
    #pragma unroll
    for (int lt = 0; lt < 4; ++lt) {
        const float* qp = Q + ((size_t)qchunk * 256 + (qg * 4 + lt) * 32 + col) * 3;
        const float qx = qp[0], qy = qp[1], qz = qp[2];
        const float ax = -2.0f * qx, ay = -2.0f * qy, az = -2.0f * qz;
        const _Float16 ahx = (_Float16)ax, ahy = (_Float16)ay, ahz = (_Float16)az;
        const _Float16 alx = (_Float16)((ax - (float)ahx) * LOSCALE);
        const _Float16 aly = (_Float16)((ay - (float)ahy) * LOSCALE);
        const _Float16 alz = (_Float16)((az - (float)ahz) * LOSCALE);
        const float qn = qx * qx + qy * qy + qz * qz;
        const _Float16 qnh = (_Float16)qn;
        const _Float16 qnl = (_Float16)((qn - (float)qnh) * LOSCALE);
        if (h == 0) {
            Ah[lt] = (half8){ahx, ahy, ahz, qnh, one, z16, z16, z16};
            Al[lt] = (half8){alx, aly, alz, ahx, ahy, ahz, qnl, one};
        } else {
            Ah[lt] = zfrag;
            Al[lt] = zfrag;
        }
        #pragma unroll
        for (int i = 0; i < 16; ++i) m[lt][i] = INFINITY;
    }

    f32x16 zc;
    #pragma unroll
    for (int i = 0; i < 16; ++i) zc[i] = 0.0f;

    const half8* bf = bfrag + (size_t)cref * 256 * 2 * 32 + col;
    const int t0 = pq * 64;

    half8 Bh0 = zfrag, Bl0 = zfrag, Bh1 = zfrag, Bl1 = zfrag;
    if (h == 0) {
        Bh0 = bf[((size_t)(t0 + 0) * 2 + 0) * 32];
        Bl0 = bf[((size_t)(t0 + 0) * 2 + 1) * 32];
        Bh1 = bf[((size_t)(t0 + 1) * 2 + 0) * 32];
        Bl1 = bf[((size_t)(t0 + 1) * 2 + 1) * 32];
    }

    #pragma unroll 1
    for (int jp = 0; jp < 32; ++jp) {
        half8 nh0 = Bh0, nl0 = Bl0, nh1 = Bh1, nl1 = Bl1;
        if (jp < 31 && h == 0) {
            const int tn = t0 + 2 * jp + 2;
            nh0 = bf[((size_t)(tn + 0) * 2 + 0) * 32];
            nl0 = bf[((size_t)(tn + 0) * 2 + 1) * 32];
            nh1 = bf[((size_t)(tn + 1) * 2 + 0) * 32];
            nl1 = bf[((size_t)(tn + 1) * 2 + 1) * 32];
        }
        #pragma unroll
        for (int lt = 0; lt < 4; ++lt) {
            f32x16 D1 = __builtin_amdgcn_mfma_f32_32x32x16_f16(Ah[lt], Bh0, zc, 0, 0, 0);
            f32x16 D2 = __builtin_amdgcn_mfma_f32_32x32x16_f16(Al[lt], Bl0, zc, 0, 0, 0);
            f32x16 E1 = __builtin_amdgcn_mfma_f32_32x32x16_f16(Ah[lt], Bh1, zc, 0, 0, 0);
            f32x16 E2 = __builtin_amdgcn_mfma_f32_32x32x16_f16(Al[lt], Bl1, zc, 0, 0, 0);
            #pragma unroll
            for (int i = 0; i < 16; ++i) {
                const float dA = fmaf(D2[i], INVLO, D1[i]);
                const float dB = fmaf(E2[i], INVLO, E1[i]);
                m[lt][i] = min3a(m[lt][i], dA, dB);
            }
        }
        Bh0 = nh0; Bl0 = nl0; Bh1 = nh1; Bl1 = nl1;
    }

    // Min over the 32 point-columns (lanes within each 32-half).
    #pragma unroll
    for (int lt = 0; lt < 4; ++lt) {
        #pragma unroll
        for (int i = 0; i < 16; ++i) {
            float v = m[lt][i];
            v = fminf(v, __shfl_xor(v, 1, 64));
            v = fminf(v, __shfl_xor(v, 2, 64));
            v = fminf(v, __shfl_xor(v, 4, 64));
            v = fminf(v, __shfl_xor(v, 8, 64));
            v = fminf(v, __shfl_xor(v, 16, 64));
            m[lt][i] = v;
        }
    }
    if (col == 0) {
        #pragma unroll
        for (int lt = 0; lt < 4; ++lt)
            #pragma unroll
            for (int i = 0; i < 16; ++i)
                red[w][lt][(i & 3) + 8 * (i >> 2) + 4 * h] = m[lt][i];
    }
    __syncthreads();

    // Combine the 4 point-quarter waves per query row; threshold; sum.
    // (Row<->query mapping is irrelevant: full dist is inside the MFMA and
    // we only SUM thresholded per-row minima — permutation-invariant.)
    double val = 0.0;
    if (threadIdx.x < 256) {
        const int gt  = threadIdx.x >> 5;   // 0..7
        const int r   = threadIdx.x & 31;
        const int qg2 = gt >> 2, lt = gt & 3;
        float mv =            red[qg2 * 4 + 0][lt][r];
        mv = fminf(mv, red[qg2 * 4 + 1][lt][r]);
        mv = fminf(mv, red[qg2 * 4 + 2][lt][r]);
        mv = fminf(mv, red[qg2 * 4 + 3][lt][r]);
        val = (mv <= *thp) ? 0.0 : (double)mv;
    }
    for (int off = 32; off > 0; off >>= 1)
        val += __shfl_down(val, off, 64);
    if (lane == 0) wsum[w] = val;
    __syncthreads();
    if (threadIdx.x == 0) {
        double s = 0.0;
        #pragma unroll
        for (int i = 0; i < 8; ++i) s += wsum[i];
        partial[bid] = s;
    }
}

// out[b] = (sum of the 64 partials of batch b) / 8192  (mean d1 + mean d2).
__global__ __launch_bounds__(256) void chamfer_fin(
    const double* __restrict__ partial,
    float* __restrict__ out)
{
    const int b = threadIdx.x >> 6;         // wave id = batch
    const int l = threadIdx.x & 63;
    double v = (l < 32) ? partial[b * 32 + l]
                        : partial[(4 + b) * 32 + (l - 32)];
    for (int off = 32; off > 0; off >>= 1)
        v += __shfl_down(v, off, 64);
    if (l == 0) out[b] = (float)(v / (double)NPTS);
}

extern "C" void kernel_launch(void* const* d_in, const int* in_sizes, int n_in,
                              void* d_out, int out_size, void* d_ws, size_t ws_size,
                              hipStream_t stream) {
    const float* xyz1 = (const float*)d_in[0];
    const float* xyz2 = (const float*)d_in[1];
    const float* thp  = (const float*)d_in[2];
    float* out        = (float*)d_out;

    half8*  bfrag   = (half8*)d_ws;         // 8*256*2*32*16 B = 2 MiB
    double* partial = (double*)((char*)d_ws + (size_t)8 * 256 * 2 * 32 * 16);

    prep_bfrag<<<256, 256, 0, stream>>>(xyz1, xyz2, bfrag);
    chamfer_mfma<<<256, 512, 0, stream>>>(xyz1, xyz2, bfrag, thp, partial);
    chamfer_fin<<<1, 256, 0, stream>>>(partial, out);
}